// Round 1
// baseline (30.983 us; speedup 1.0000x reference)
//
#include <hip/hip_runtime.h>
#include <math.h>

#define NQ 4
#define NL 2
#define INF 8
#define OUTF 128

__global__ __launch_bounds__(256) void tq_kernel(
    const float* __restrict__ x,       // [B,8]
    const float* __restrict__ W_pre,   // [4,8]
    const float* __restrict__ b_pre,   // [4]
    const float* __restrict__ theta,   // [2,4]
    const float* __restrict__ W_post,  // [128,4]
    const float* __restrict__ b_post,  // [128]
    float* __restrict__ out,           // [B,128]
    int B)
{
    const int tid = threadIdx.x;
    const int row = blockIdx.x * 256 + tid;

    __shared__ float zsh[256][4];

    if (row < B) {
        // ---- phase 1: embedding angles ----
        const float4* xr = reinterpret_cast<const float4*>(x + (size_t)row * INF);
        float4 xa = xr[0];
        float4 xb = xr[1];

        float ca[NQ], sa[NQ];
        #pragma unroll
        for (int w = 0; w < NQ; ++w) {
            const float* wp = W_pre + w * INF;   // wave-uniform -> s_load
            float acc = b_pre[w];
            acc += xa.x * wp[0] + xa.y * wp[1] + xa.z * wp[2] + xa.w * wp[3];
            acc += xb.x * wp[4] + xb.y * wp[5] + xb.z * wp[6] + xb.w * wp[7];
            float alpha = 3.14159265358979323846f * tanhf(acc);
            __sincosf(0.5f * alpha, &sa[w], &ca[w]);
        }

        // trainable angles (uniform across batch)
        float ct[NL][NQ], st_[NL][NQ];
        #pragma unroll
        for (int l = 0; l < NL; ++l)
            #pragma unroll
            for (int w = 0; w < NQ; ++w)
                __sincosf(0.5f * theta[l * NQ + w], &st_[l][w], &ct[l][w]);

        // ---- phase 2: statevector sim (wire w <-> bit (3-w), mask 8>>w) ----
        // product-state init = the 4 embedding RYs applied to |0000>
        float st[16];
        #pragma unroll
        for (int i = 0; i < 16; ++i) {
            float v = (i & 8) ? sa[0] : ca[0];
            v *= (i & 4) ? sa[1] : ca[1];
            v *= (i & 2) ? sa[2] : ca[2];
            v *= (i & 1) ? sa[3] : ca[3];
            st[i] = v;
        }

        #pragma unroll
        for (int l = 0; l < NL; ++l) {
            // RY(theta[l][w]) on each wire
            #pragma unroll
            for (int w = 0; w < NQ; ++w) {
                const float c = ct[l][w], s = st_[l][w];
                const int bit = 8 >> w;
                #pragma unroll
                for (int i = 0; i < 16; ++i) {
                    if (!(i & bit)) {
                        const int j = i | bit;
                        float a0 = st[i], a1 = st[j];
                        st[i] = c * a0 - s * a1;
                        st[j] = s * a0 + c * a1;
                    }
                }
            }
            // CNOT chain (w, w+1): if ctrl bit set, flip tgt bit (register swap)
            #pragma unroll
            for (int w = 0; w < NQ - 1; ++w) {
                const int cb = 8 >> w, tb = 8 >> (w + 1);
                #pragma unroll
                for (int i = 0; i < 16; ++i) {
                    if ((i & cb) && !(i & tb)) {
                        const int j = i | tb;
                        float t = st[i]; st[i] = st[j]; st[j] = t;
                    }
                }
            }
        }

        // ---- phase 3: PauliZ expectations ----
        float p[16];
        #pragma unroll
        for (int i = 0; i < 16; ++i) p[i] = st[i] * st[i];

        #pragma unroll
        for (int w = 0; w < NQ; ++w) {
            const int bit = 8 >> w;
            float zp = 0.f, zm = 0.f;
            #pragma unroll
            for (int i = 0; i < 16; ++i) {
                if (i & bit) zm += p[i]; else zp += p[i];
            }
            zsh[tid][w] = zp - zm;
        }
    }
    __syncthreads();

    // ---- phase 4: coalesced post-GEMV epilogue ----
    // wave wv handles rows [block*256 + wv*64, +64); lane owns cols 2l, 2l+1
    const int lane = tid & 63;
    const int wv = tid >> 6;
    const int c0 = 2 * lane;

    const float4 wpA = *reinterpret_cast<const float4*>(W_post + c0 * NQ);
    const float4 wpB = *reinterpret_cast<const float4*>(W_post + (c0 + 1) * NQ);
    const float2 bp = *reinterpret_cast<const float2*>(b_post + c0);

    const int rbase = blockIdx.x * 256 + wv * 64;
    #pragma unroll 4
    for (int r = 0; r < 64; ++r) {
        if (rbase + r >= B) break;
        const float z0 = zsh[wv * 64 + r][0];
        const float z1 = zsh[wv * 64 + r][1];
        const float z2 = zsh[wv * 64 + r][2];
        const float z3 = zsh[wv * 64 + r][3];
        float2 o;
        o.x = bp.x + z0 * wpA.x + z1 * wpA.y + z2 * wpA.z + z3 * wpA.w;
        o.y = bp.y + z0 * wpB.x + z1 * wpB.y + z2 * wpB.z + z3 * wpB.w;
        *reinterpret_cast<float2*>(out + (size_t)(rbase + r) * OUTF + c0) = o;
    }
}

extern "C" void kernel_launch(void* const* d_in, const int* in_sizes, int n_in,
                              void* d_out, int out_size, void* d_ws, size_t ws_size,
                              hipStream_t stream) {
    const float* x      = (const float*)d_in[0];
    const float* W_pre  = (const float*)d_in[1];
    const float* b_pre  = (const float*)d_in[2];
    const float* theta  = (const float*)d_in[3];
    const float* W_post = (const float*)d_in[4];
    const float* b_post = (const float*)d_in[5];
    float* out = (float*)d_out;

    const int B = in_sizes[0] / INF;
    const int nblocks = (B + 255) / 256;
    tq_kernel<<<dim3(nblocks), dim3(256), 0, stream>>>(
        x, W_pre, b_pre, theta, W_post, b_post, out, B);
}

// Round 3
// 29.541 us; speedup vs baseline: 1.0488x; 1.0488x over previous
//
#include <hip/hip_runtime.h>
#include <math.h>

#define NQ 4
#define NL 2
#define INF 8
#define OUTF 128

typedef float fv4 __attribute__((ext_vector_type(4)));

__device__ __forceinline__ float fast_tanh(float x) {
    // tanh(x) = 1 - 2/(e^{2x}+1); |err| < 1e-6 over useful range
    float e = __expf(2.0f * x);
    return 1.0f - 2.0f / (e + 1.0f);
}

__global__ __launch_bounds__(256) void tq_kernel(
    const float* __restrict__ x,       // [B,8]
    const float* __restrict__ W_pre,   // [4,8]
    const float* __restrict__ b_pre,   // [4]
    const float* __restrict__ theta,   // [2,4]
    const float* __restrict__ W_post,  // [128,4]
    const float* __restrict__ b_post,  // [128]
    float* __restrict__ out,           // [B,128]
    int B)
{
    const int tid = threadIdx.x;
    const int row = blockIdx.x * 256 + tid;

    __shared__ float zsh[256][4];

    if (row < B) {
        // ---- phase 1: embedding angles ----
        const float4* xr = reinterpret_cast<const float4*>(x + (size_t)row * INF);
        float4 xa = xr[0];
        float4 xb = xr[1];

        float ca[NQ], sa[NQ];
        #pragma unroll
        for (int w = 0; w < NQ; ++w) {
            const float* wp = W_pre + w * INF;   // wave-uniform -> scalar loads
            float acc = b_pre[w];
            acc += xa.x * wp[0] + xa.y * wp[1] + xa.z * wp[2] + xa.w * wp[3];
            acc += xb.x * wp[4] + xb.y * wp[5] + xb.z * wp[6] + xb.w * wp[7];
            float alpha = 3.14159265358979323846f * fast_tanh(acc);
            __sincosf(0.5f * alpha, &sa[w], &ca[w]);
        }

        // trainable angles (uniform across batch)
        float ct[NL][NQ], st_[NL][NQ];
        #pragma unroll
        for (int l = 0; l < NL; ++l)
            #pragma unroll
            for (int w = 0; w < NQ; ++w)
                __sincosf(0.5f * theta[l * NQ + w], &st_[l][w], &ct[l][w]);

        // ---- phase 2: statevector sim (wire w <-> bit mask 8>>w) ----
        // product-state init = 4 embedding RYs applied to |0000>
        float st[16];
        #pragma unroll
        for (int i = 0; i < 16; ++i) {
            float v = (i & 8) ? sa[0] : ca[0];   // compile-time select (i unrolled)
            v *= (i & 4) ? sa[1] : ca[1];
            v *= (i & 2) ? sa[2] : ca[2];
            v *= (i & 1) ? sa[3] : ca[3];
            st[i] = v;
        }

        #pragma unroll
        for (int l = 0; l < NL; ++l) {
            #pragma unroll
            for (int w = 0; w < NQ; ++w) {
                const float c = ct[l][w], s = st_[l][w];
                const int bit = 8 >> w;
                #pragma unroll
                for (int i = 0; i < 16; ++i) {
                    if (!(i & bit)) {
                        const int j = i | bit;
                        float a0 = st[i], a1 = st[j];
                        st[i] = c * a0 - s * a1;
                        st[j] = s * a0 + c * a1;
                    }
                }
            }
            // CNOT chain: pure compile-time register permutation
            #pragma unroll
            for (int w = 0; w < NQ - 1; ++w) {
                const int cb = 8 >> w, tb = 8 >> (w + 1);
                #pragma unroll
                for (int i = 0; i < 16; ++i) {
                    if ((i & cb) && !(i & tb)) {
                        const int j = i | tb;
                        float t = st[i]; st[i] = st[j]; st[j] = t;
                    }
                }
            }
        }

        // ---- phase 3: PauliZ expectations ----
        float p[16];
        #pragma unroll
        for (int i = 0; i < 16; ++i) p[i] = st[i] * st[i];

        #pragma unroll
        for (int w = 0; w < NQ; ++w) {
            const int bit = 8 >> w;
            float zp = 0.f, zm = 0.f;
            #pragma unroll
            for (int i = 0; i < 16; ++i) {
                if (i & bit) zm += p[i]; else zp += p[i];
            }
            zsh[tid][w] = zp - zm;
        }
    }
    __syncthreads();

    // ---- phase 4: coalesced float4 epilogue ----
    // lane owns 4 consecutive cols of one row; 32 lanes cover a 512B row;
    // a wave writes 2 rows (1 KiB) per dwordx4 store instruction.
    const int lane  = tid & 63;
    const int wv    = tid >> 6;
    const int colb  = (lane & 31) * 4;   // column block [colb, colb+3]
    const int rhalf = lane >> 5;         // 0 or 1: which of the 2 rows/iter

    const float4 w0 = *reinterpret_cast<const float4*>(W_post + (colb + 0) * NQ);
    const float4 w1 = *reinterpret_cast<const float4*>(W_post + (colb + 1) * NQ);
    const float4 w2 = *reinterpret_cast<const float4*>(W_post + (colb + 2) * NQ);
    const float4 w3 = *reinterpret_cast<const float4*>(W_post + (colb + 3) * NQ);
    const float4 bp = *reinterpret_cast<const float4*>(b_post + colb);

    const int lr0   = wv * 64 + rhalf;
    const int rbase = blockIdx.x * 256 + wv * 64 + rhalf;

    if (rbase + 62 < B) {
        // full block: no per-iter guard
        fv4* optr = reinterpret_cast<fv4*>(out + (size_t)rbase * OUTF + colb);
        #pragma unroll 8
        for (int r = 0; r < 32; ++r) {
            const int lr = lr0 + 2 * r;
            const float4 z = *reinterpret_cast<const float4*>(&zsh[lr][0]);
            fv4 o;
            o.x = fmaf(z.w, w0.w, fmaf(z.z, w0.z, fmaf(z.y, w0.y, fmaf(z.x, w0.x, bp.x))));
            o.y = fmaf(z.w, w1.w, fmaf(z.z, w1.z, fmaf(z.y, w1.y, fmaf(z.x, w1.x, bp.y))));
            o.z = fmaf(z.w, w2.w, fmaf(z.z, w2.z, fmaf(z.y, w2.y, fmaf(z.x, w2.x, bp.z))));
            o.w = fmaf(z.w, w3.w, fmaf(z.z, w3.z, fmaf(z.y, w3.y, fmaf(z.x, w3.x, bp.w))));
            __builtin_nontemporal_store(o, optr + (size_t)2 * r * (OUTF / 4));
        }
    } else {
        for (int r = 0; r < 32; ++r) {
            const int rr = rbase + 2 * r;
            if (rr >= B) break;
            const int lr = lr0 + 2 * r;
            const float4 z = *reinterpret_cast<const float4*>(&zsh[lr][0]);
            float4 o;
            o.x = fmaf(z.w, w0.w, fmaf(z.z, w0.z, fmaf(z.y, w0.y, fmaf(z.x, w0.x, bp.x))));
            o.y = fmaf(z.w, w1.w, fmaf(z.z, w1.z, fmaf(z.y, w1.y, fmaf(z.x, w1.x, bp.y))));
            o.z = fmaf(z.w, w2.w, fmaf(z.z, w2.z, fmaf(z.y, w2.y, fmaf(z.x, w2.x, bp.z))));
            o.w = fmaf(z.w, w3.w, fmaf(z.z, w3.z, fmaf(z.y, w3.y, fmaf(z.x, w3.x, bp.w))));
            *reinterpret_cast<float4*>(out + (size_t)rr * OUTF + colb) = o;
        }
    }
}

extern "C" void kernel_launch(void* const* d_in, const int* in_sizes, int n_in,
                              void* d_out, int out_size, void* d_ws, size_t ws_size,
                              hipStream_t stream) {
    const float* x      = (const float*)d_in[0];
    const float* W_pre  = (const float*)d_in[1];
    const float* b_pre  = (const float*)d_in[2];
    const float* theta  = (const float*)d_in[3];
    const float* W_post = (const float*)d_in[4];
    const float* b_post = (const float*)d_in[5];
    float* out = (float*)d_out;

    const int B = in_sizes[0] / INF;
    const int nblocks = (B + 255) / 256;
    tq_kernel<<<dim3(nblocks), dim3(256), 0, stream>>>(
        x, W_pre, b_pre, theta, W_post, b_post, out, B);
}